// Round 11
// baseline (8080.289 us; speedup 1.0000x reference)
//
#include <hip/hip_runtime.h>
#include <hip/hip_bf16.h>
#include <hip/hip_fp16.h>

// ---------------------------------------------------------------------------
// 4-layer LSTM (H=1024, B=64, T=256) + FC, persistent pipelined kernel.
// R15: R14 (full w_hh in 160KiB LDS, 4 partial bufs, dataflow waits,
//      unroll-4, fresh ring) with the publish DECOUPLED from the block:
//      - bar2 removed in fresh mode. Publish is PER-WAVE: lane 0 of each
//        wave release-stores flag[wg].int[wave]=s right after its own EW
//        (release = that wave's vmcnt drains -> h stores acked at IF$).
//      - Consumers poll all-4 ints per producer line (2 x u64 loads, same
//        line -> no extra poll traffic).
//      - WAR on shared partial bufs without bar2: every wave also polls its
//        OWN block's line >= s-1 before the iteration (own line >= s-1 =>
//        all 4 waves finished EW(s-1), the only readers of the buffer this
//        wave is about to overwrite). Only bar1 remains per step.
//      Rationale: period ~12.9us vs ~3.5us modelled chain; the gap is
//      cross-block convoy coupling. Publish time was max-over-4-waves +
//      full-block vmcnt barrier; now it's per-wave. Fallback (!fresh):
//      R14 structure with bar2 + tid0 publish (writes all 4 ints).
// ---------------------------------------------------------------------------

#define H      1024
#define BATCH  64
#define T      256
#define RINGN  8

typedef _Float16 f16x8 __attribute__((ext_vector_type(8)));
typedef _Float16 f16x4 __attribute__((ext_vector_type(4)));
typedef float    f32x4 __attribute__((ext_vector_type(4)));

// ws layout (bytes)
#define WPACK_HH_SZ  (4ull*64*32*4*64*8*2)           // 33554432: [l][wg][ks][nt][lane][8] f16
#define WPACK_IH_SZ  (3ull*64*32*4*64*8*2)           // 25165824
#define HRING_OFF    (WPACK_HH_SZ + WPACK_IH_SZ)     // 58720256
#define SLOT_ELEMS   65536                           // per (l,slot): 64 batch x 1024 units f16
#define SLOT_BYTES   131072ull
#define CNT_INTS     (4*257*16)                      // flag/cnt2 region, 64B-padded entries
#define CNT_BYTES    ((unsigned long long)CNT_INTS*4)

__host__ __device__ __forceinline__ unsigned long long ring_bytes(int nslot) {
  return 4ull*(unsigned)nslot*SLOT_BYTES;
}
__device__ __forceinline__ int cidx(int l, int s) { return (l*257 + s)*16; }
// per-producer flag line: one 64B line per (layer, wg); ints 0..3 = per-wave
__device__ __forceinline__ int fidx(int l, int w) { return (l*64 + w)*16; }

// fresh mode: bit-reversed slot index kills any sequential-prefetch adjacency
__device__ __forceinline__ int aslot(int s, int fresh) {
  if (!fresh) return s & 7;
  return (s >= 256) ? 256 : (int)(__brev((unsigned)s) >> 24);
}

__device__ __forceinline__ void wait_eq64(int* p) {
  int it = 0;
  while (__hip_atomic_load(p, __ATOMIC_RELAXED, __HIP_MEMORY_SCOPE_AGENT) < 64) {
    __builtin_amdgcn_s_sleep(1);
    if (++it > 100000000) break;   // failsafe: never hang the harness
  }
}

// poll one producer line's 4 per-wave flags until all >= tgt (2 u64 loads/iter)
__device__ __forceinline__ void wait_all4_ge(const int* p, int tgt) {
  const unsigned long long* q = (const unsigned long long*)p;
  int it = 0;
  for (;;) {
    unsigned long long ab = __hip_atomic_load(q,     __ATOMIC_RELAXED, __HIP_MEMORY_SCOPE_AGENT);
    unsigned long long cd = __hip_atomic_load(q + 1, __ATOMIC_RELAXED, __HIP_MEMORY_SCOPE_AGENT);
    int a = (int)ab, b = (int)(ab >> 32);
    int c = (int)cd, d = (int)(cd >> 32);
    if (a >= tgt && b >= tgt && c >= tgt && d >= tgt) break;
    __builtin_amdgcn_s_sleep(1);
    if (++it > 50000000) break;    // failsafe
  }
}

__device__ __forceinline__ f16x8 load_h8_sc(const _Float16* p) {
  const unsigned long long* q = (const unsigned long long*)p;
  unsigned long long lo = __hip_atomic_load(q,     __ATOMIC_RELAXED, __HIP_MEMORY_SCOPE_AGENT);
  unsigned long long hi = __hip_atomic_load(q + 1, __ATOMIC_RELAXED, __HIP_MEMORY_SCOPE_AGENT);
  union { unsigned long long u[2]; f16x8 v; } c;
  c.u[0] = lo; c.u[1] = hi;
  return c.v;
}

// --- pack weights fp32 -> fp16 MFMA-fragment layout; zero h ring slot 0; preset flags=0
__global__ void pack_kernel(const float* __restrict__ w_ih_rest,
                            const float* __restrict__ w_hh,
                            char* __restrict__ ws, int nslot)
{
  const long long NS_HH = 4ll*64*32*4*64;   // 2097152
  const long long NS_IH = 3ll*64*32*4*64;   // 1572864
  const long long NS_HZ = 4ll*8192;         // uint4 slots to zero slot-0 of each layer ring
  const long long NTOT  = NS_HH + NS_IH + NS_HZ + 1024;
  _Float16* whh_dst = (_Float16*)ws;
  _Float16* wih_dst = (_Float16*)(ws + WPACK_HH_SZ);
  int* cnt = (int*)(ws + HRING_OFF + ring_bytes(nslot));
  for (long long i = blockIdx.x*(long long)blockDim.x + threadIdx.x; i < NTOT;
       i += (long long)gridDim.x*blockDim.x) {
    if (i < NS_HH + NS_IH) {
      const bool is_hh = (i < NS_HH);
      long long slot = is_hh ? i : (i - NS_HH);
      long long j = slot;
      int lane = (int)(j & 63); j >>= 6;
      int nt   = (int)(j & 3);  j >>= 2;
      int ks   = (int)(j & 31); j >>= 5;
      int wg   = (int)(j & 63); j >>= 6;
      int l    = (int)j;
      int row = nt*1024 + wg*16 + (lane & 15);      // global gate row (nt = gate: i,f,g,o)
      int col = ks*32 + (lane >> 4)*8;
      const float* src = (is_hh ? w_hh : w_ih_rest) + ((long long)l*4096 + row)*1024 + col;
      f16x8 v;
      #pragma unroll
      for (int e = 0; e < 8; e++) v[e] = (_Float16)src[e];
      *(f16x8*)((is_hh ? whh_dst : wih_dst) + slot*8) = v;
    } else if (i < NS_HH + NS_IH + NS_HZ) {
      long long j = i - (NS_HH + NS_IH);
      long long l = j >> 13;            // /8192
      long long off = j & 8191;
      uint4 z = make_uint4(0,0,0,0);
      ((uint4*)(ws + HRING_OFF))[(l*(long long)nslot)*8192 + off] = z;  // zero h[l][slot0]
    } else {
      long long j = i - (NS_HH + NS_IH + NS_HZ);    // 0..1023 = (l*64+wg)*4 + w
      int line = (int)(j >> 2), w = (int)(j & 3);
      cnt[line*16 + w] = 0;                         // per-wave flag: "step 0 published"
    }
  }
}

template <int NKS>   // #ks of w_hh staged in LDS (32 = full; 28 = reduced fallback)
__global__ __launch_bounds__(256, 1) void lstm_main(
    const float* __restrict__ x,
    const float* __restrict__ wih0,
    const float* __restrict__ bih,
    const float* __restrict__ bhh,
    char* __restrict__ ws, int nslot, int fresh)
{
  // one-time agent acquire: invalidate stale L1/L2 lines from prior replays
  __builtin_amdgcn_fence(__ATOMIC_ACQUIRE, "agent");

  extern __shared__ char lds[];
  _Float16* whh_lds = (_Float16*)lds;                          // NKS*4096 B
  _Float16* bufs    = (_Float16*)(lds + (size_t)NKS*4096);     // 4 x 8192 B partials

  const int l   = blockIdx.x >> 6;
  const int wg  = blockIdx.x & 63;
  const int tid = threadIdx.x;
  const int wave = tid >> 6;
  const int lane = tid & 63;

  const _Float16* wpack_hh = (const _Float16*)ws + (size_t)(l*64 + wg)*65536;
  const _Float16* wpack_ih = (l > 0)
      ? (const _Float16*)(ws + WPACK_HH_SZ) + (size_t)((l-1)*64 + wg)*65536
      : wpack_hh;  // unused for l==0
  _Float16* hring = (_Float16*)(ws + HRING_OFF);
  int* cnt  = (int*)(ws + HRING_OFF + ring_bytes(nslot));   // per-producer flag lines
  int* cnt2 = cnt + CNT_INTS;                               // fallback backpressure (atomic)

  // stage w_hh ks 0..NKS-1 into LDS (one-time; wpack is immutable; ks-major)
  {
    const uint4* src = (const uint4*)wpack_hh;
    uint4* dst = (uint4*)whh_lds;
    for (int i = tid; i < NKS*256; i += 256) dst[i] = src[i];
  }

  // elementwise ownership: thread -> (batch b_ew, 4 consecutive hidden units u0..u0+3)
  const int b_ew = tid >> 2;
  const int u0   = (tid & 3) * 4;
  float cst[4] = {0.f, 0.f, 0.f, 0.f};
  float bias[4][4];            // [item][gate]
  float wx0[4][4], wx1[4][4];  // layer-0 input weights (K=2 handled in VALU)
  #pragma unroll
  for (int ii = 0; ii < 4; ii++) {
    #pragma unroll
    for (int g = 0; g < 4; g++) {
      int row = g*1024 + wg*16 + u0 + ii;
      bias[ii][g] = bih[l*4096 + row] + bhh[l*4096 + row];
      if (l == 0) { wx0[ii][g] = wih0[row*2]; wx1[ii][g] = wih0[row*2 + 1]; }
      else        { wx0[ii][g] = 0.f;         wx1[ii][g] = 0.f; }
    }
  }
  __syncthreads();

  const int m_row = lane & 15, quad = lane >> 4;

  for (int s = 1; s <= T; s++) {
    if (fresh) {
      // per-wave dataflow waits; NO pre-GEMM barrier. Each wave polls the
      // producer lines its GEMM segment reads (all-4 per line), PLUS its
      // own block's line >= s-1 (WAR guard for the partial buffers: own
      // line >= s-1 means all 4 waves finished EW(s-1)).
      if (l == 0) {
        if (lane < 16)       wait_all4_ge(cnt + fidx(0, wave*16 + lane), s - 1);
        else if (lane == 32) wait_all4_ge(cnt + fidx(0, wg), s - 1);
      } else {
        if (wave == 0)      { if (lane < 32) wait_all4_ge(cnt + fidx(l-1, lane),      s);
                              else if (lane == 32) wait_all4_ge(cnt + fidx(l, wg), s - 1); }
        else if (wave == 1) { if (lane < 32) wait_all4_ge(cnt + fidx(l-1, 32 + lane), s);
                              else if (lane == 32) wait_all4_ge(cnt + fidx(l, wg), s - 1); }
        else if (wave == 2) { if (lane < 32) wait_all4_ge(cnt + fidx(l,   lane),      s - 1);
                              else if (lane == 32) wait_all4_ge(cnt + fidx(l, wg), s - 1); }
        else                { if (lane < 32) wait_all4_ge(cnt + fidx(l,   32 + lane), s - 1);
                              else if (lane == 32) wait_all4_ge(cnt + fidx(l, wg), s - 1); }
      }
    } else {
      // fallback: wide waits + barriers (ring-reuse mode)
      if (wave == 0) {
        wait_all4_ge(cnt + fidx(l, lane), s - 1);
      } else if (wave == 1) {
        if (l > 0) wait_all4_ge(cnt + fidx(l - 1, lane), s);
      } else if (tid == 128) {
        if (l < 3 && s > RINGN) wait_eq64(&cnt2[cidx(l, s-RINGN)]);
      }
      __syncthreads();
    }

    // A source: for l>0 waves 0-1 consume h_below[s] (with w_ih), waves 2-3 h_own[s-1] (w_hh)
    const _Float16* asrc = (l > 0 && wave < 2)
        ? hring + ((size_t)(l-1)*nslot + aslot(s,   fresh))*SLOT_ELEMS
        : hring + ((size_t)l*nslot     + aslot(s-1, fresh))*SLOT_ELEMS;

    f32x4 acc[4][4];
    #pragma unroll
    for (int mt = 0; mt < 4; mt++)
      #pragma unroll
      for (int nt = 0; nt < 4; nt++) acc[mt][nt] = (f32x4){0.f, 0.f, 0.f, 0.f};

    // b from LDS (w_hh ks<NKS)
    auto kb_lds = [&](int ks, bool plain) {
      const int kb = ks*32 + quad*8;
      f16x8 a[4], bb[4];
      #pragma unroll
      for (int mt = 0; mt < 4; mt++) {
        const _Float16* ap = asrc + (size_t)(mt*16 + m_row)*1024 + kb;
        a[mt] = plain ? *(const f16x8*)ap : load_h8_sc(ap);
      }
      #pragma unroll
      for (int nt = 0; nt < 4; nt++)
        bb[nt] = *(const f16x8*)(whh_lds + ((ks*4 + nt)*64 + lane)*8);
      #pragma unroll
      for (int mt = 0; mt < 4; mt++)
        #pragma unroll
        for (int nt = 0; nt < 4; nt++)
          acc[mt][nt] = __builtin_amdgcn_mfma_f32_16x16x32_f16(a[mt], bb[nt], acc[mt][nt], 0, 0, 0);
    };
    // b from global (w_ih stream, or w_hh spill ks>=NKS in fallback template)
    auto kb_glob = [&](int ks, const _Float16* bsrc, bool plain) {
      const int kb = ks*32 + quad*8;
      f16x8 a[4], bb[4];
      #pragma unroll
      for (int mt = 0; mt < 4; mt++) {
        const _Float16* ap = asrc + (size_t)(mt*16 + m_row)*1024 + kb;
        a[mt] = plain ? *(const f16x8*)ap : load_h8_sc(ap);
      }
      #pragma unroll
      for (int nt = 0; nt < 4; nt++)
        bb[nt] = *(const f16x8*)(bsrc + ((size_t)(ks*4 + nt)*64 + lane)*8);
      #pragma unroll
      for (int mt = 0; mt < 4; mt++)
        #pragma unroll
        for (int nt = 0; nt < 4; nt++)
          acc[mt][nt] = __builtin_amdgcn_mfma_f32_16x16x32_f16(a[mt], bb[nt], acc[mt][nt], 0, 0, 0);
    };

    const bool pl = (fresh != 0);
    if (l == 0) {
      if (NKS >= 32 || wave < 3) {
        #pragma unroll 4
        for (int i = 0; i < 8; i++) kb_lds(wave*8 + i, pl);
      } else {  // NKS==28, wave 3: ks 24..27 LDS, 28..31 global
        #pragma unroll 4
        for (int i = 0; i < 4; i++) kb_lds(24 + i, pl);
        #pragma unroll
        for (int i = 0; i < 4; i++) kb_glob(28 + i, wpack_hh, pl);
      }
    } else if (wave < 2) {
      #pragma unroll 4
      for (int i = 0; i < 16; i++) kb_glob(wave*16 + i, wpack_ih, pl);
    } else if (wave == 2) {
      #pragma unroll 4
      for (int i = 0; i < 16; i++) kb_lds(i, pl);
    } else {
      #pragma unroll 4
      for (int i = 0; i < (NKS - 16); i++) kb_lds(16 + i, pl);
      #pragma unroll
      for (int i = NKS - 16; i < 16; i++) kb_glob(16 + i, wpack_hh, pl);
    }

    // every wave writes its own partial buffer (no add pass)
    {
      _Float16* mybuf = bufs + (size_t)wave*4096;   // 8192 B each
      #pragma unroll
      for (int mt = 0; mt < 4; mt++)
        #pragma unroll
        for (int nt = 0; nt < 4; nt++) {
          f16x4 v;
          #pragma unroll
          for (int e = 0; e < 4; e++) v[e] = (_Float16)acc[mt][nt][e];
          *(f16x4*)(mybuf + ((mt*4 + nt)*64 + lane)*4) = v;
        }
    }
    // ring backpressure signal only needed when slots are reused (fallback mode)
    if (!fresh && tid == 0 && l > 0)
      __hip_atomic_fetch_add(&cnt2[cidx(l-1, s)], 1, __ATOMIC_RELAXED, __HIP_MEMORY_SCOPE_AGENT);
    __syncthreads();   // bar1: all partials visible (also: h reads complete)

    // elementwise gates -> c,h  (fp32); sums 4 partial bufs directly
    {
      const int mt = b_ew >> 4, q = (b_ew & 15) >> 2, reg = b_ew & 3;
      float xs0 = 0.f, xs1 = 0.f;
      if (l == 0) {
        xs0 = x[((size_t)b_ew*T + (s-1))*2];
        xs1 = x[((size_t)b_ew*T + (s-1))*2 + 1];
      }
      f16x4 hv;
      #pragma unroll
      for (int ii = 0; ii < 4; ii++) {
        const int u = u0 + ii;
        float pre[4];
        #pragma unroll
        for (int g = 0; g < 4; g++) {
          int idx = ((mt*4 + g)*64 + (u + 16*q))*4 + reg;
          pre[g] = (float)bufs[idx] + (float)bufs[4096 + idx]
                 + (float)bufs[8192 + idx] + (float)bufs[12288 + idx]
                 + bias[ii][g] + wx0[ii][g]*xs0 + wx1[ii][g]*xs1;
        }
        float ig = 1.f/(1.f + __expf(-pre[0]));
        float fg = 1.f/(1.f + __expf(-pre[1]));
        float gg = 2.f/(1.f + __expf(-2.f*pre[2])) - 1.f;
        float og = 1.f/(1.f + __expf(-pre[3]));
        float c  = fg*cst[ii] + ig*gg;
        cst[ii] = c;
        float th = 2.f/(1.f + __expf(-2.f*c)) - 1.f;
        hv[ii] = (_Float16)(og*th);
      }
      _Float16* hdst = hring + ((size_t)l*nslot + aslot(s, fresh))*SLOT_ELEMS
                     + (size_t)b_ew*1024 + wg*16 + u0;
      union { f16x4 v; unsigned long long u; } cv; cv.v = hv;
      // sc write-through: IF$ (coherence point) holds the authoritative copy
      __hip_atomic_store((unsigned long long*)hdst, cv.u,
                         __ATOMIC_RELAXED, __HIP_MEMORY_SCOPE_AGENT);
    }

    if (fresh) {
      // per-wave publish: RELEASE drains this wave's h-stores (vmcnt) to the
      // coherence point, then flags its int on the block's line. No barrier.
      if (lane == 0)
        __hip_atomic_store(cnt + fidx(l, wg) + wave, s,
                           __ATOMIC_RELEASE, __HIP_MEMORY_SCOPE_AGENT);
    } else {
      __syncthreads();   // bar2: h stores acked before publish
      if (tid == 0) {
        __hip_atomic_store(cnt + fidx(l, wg) + 0, s, __ATOMIC_RELAXED, __HIP_MEMORY_SCOPE_AGENT);
        __hip_atomic_store(cnt + fidx(l, wg) + 1, s, __ATOMIC_RELAXED, __HIP_MEMORY_SCOPE_AGENT);
        __hip_atomic_store(cnt + fidx(l, wg) + 2, s, __ATOMIC_RELAXED, __HIP_MEMORY_SCOPE_AGENT);
        __hip_atomic_store(cnt + fidx(l, wg) + 3, s, __ATOMIC_RELAXED, __HIP_MEMORY_SCOPE_AGENT);
      }
    }
  }
}

__global__ void fc_kernel(const char* __restrict__ ws,
                          const float* __restrict__ fcw,
                          const float* __restrict__ fcb,
                          float* __restrict__ out, int nslot, int fresh)
{
  const _Float16* h3 = (const _Float16*)(ws + HRING_OFF)
                     + ((size_t)3*nslot + aslot(T, fresh))*SLOT_ELEMS;  // layer 3, t=256
  __shared__ float red[256];
  const int tid = threadIdx.x;
  const int b = tid >> 2, p = tid & 3;
  float sum = 0.f;
  for (int j = p*256; j < p*256 + 256; j++)
    sum += fcw[j] * (float)h3[(size_t)b*1024 + j];
  red[tid] = sum;
  __syncthreads();
  if (p == 0)
    out[b] = red[tid] + red[tid+1] + red[tid+2] + red[tid+3] + fcb[0];
}

extern "C" void kernel_launch(void* const* d_in, const int* in_sizes, int n_in,
                              void* d_out, int out_size, void* d_ws, size_t ws_size,
                              hipStream_t stream)
{
  const float* x    = (const float*)d_in[0];
  const float* wih0 = (const float*)d_in[1];
  const float* wihr = (const float*)d_in[2];
  const float* whh  = (const float*)d_in[3];
  const float* bih  = (const float*)d_in[4];
  const float* bhh  = (const float*)d_in[5];
  const float* fcw  = (const float*)d_in[6];
  const float* fcb  = (const float*)d_in[7];
  float* out = (float*)d_out;
  char* ws = (char*)d_ws;
  (void)in_sizes; (void)n_in; (void)out_size;

  const unsigned long long ws_big   = HRING_OFF + ring_bytes(257) + 2*CNT_BYTES; // ~193.6 MB
  const unsigned long long ws_small = HRING_OFF + ring_bytes(8)   + 2*CNT_BYTES; // ~63 MB
  if (ws_size < ws_small) return;
  const int fresh = (ws_size >= ws_big) ? 1 : 0;
  const int nslot = fresh ? 257 : 8;

  // try full 160 KiB workgroup LDS (32-ks w_hh + partials); fall back to
  // 147456 (28-ks) if the opt-in is rejected. Host-side, idempotent,
  // capture-safe.
  hipError_t eFull = hipFuncSetAttribute(
      reinterpret_cast<const void*>(lstm_main<32>),
      hipFuncAttributeMaxDynamicSharedMemorySize, 163840);
  if (eFull != hipSuccess)
    hipFuncSetAttribute(reinterpret_cast<const void*>(lstm_main<28>),
                        hipFuncAttributeMaxDynamicSharedMemorySize, 147456);

  hipMemsetAsync(ws + HRING_OFF + ring_bytes(nslot), 0, (size_t)(2*CNT_BYTES), stream);
  pack_kernel<<<512, 256, 0, stream>>>(wihr, whh, ws, nslot);
  if (eFull == hipSuccess)
    lstm_main<32><<<256, 256, 163840, stream>>>(x, wih0, bih, bhh, ws, nslot, fresh);
  else
    lstm_main<28><<<256, 256, 147456, stream>>>(x, wih0, bih, bhh, ws, nslot, fresh);
  fc_kernel<<<1, 256, 0, stream>>>(ws, fcw, fcb, out, nslot, fresh);
}